// Round 4
// baseline (996.792 us; speedup 1.0000x reference)
//
#include <hip/hip_runtime.h>
#include <math.h>

#define Bb 4
#define Cc 8
#define Ss 512
#define Ee 512
#define Hh 8
#define HDd 64
#define LOCALW 32
#define NTOK (Bb*Cc*Ss)   // 16384 rows
#define RS 40             // P-scratch row stride (shorts): 80 B, 16B-aligned, odd bank factor

typedef __attribute__((ext_vector_type(8))) __bf16 bf16x8;
typedef __attribute__((ext_vector_type(4))) float floatx4;
typedef __attribute__((ext_vector_type(4))) unsigned short ushort4v;

__device__ __forceinline__ unsigned short f2bf(float f) {
  union { float f; unsigned int i; } x; x.f = f;
  unsigned int r = x.i + 0x7fffu + ((x.i >> 16) & 1u);  // RNE
  return (unsigned short)(r >> 16);
}

// Convert q,k,v fp32 -> bf16 (blockIdx.y selects tensor)
__global__ __launch_bounds__(256) void cvt3_f32_bf16(
    const float4* __restrict__ s0, const float4* __restrict__ s1, const float4* __restrict__ s2,
    ushort4v* __restrict__ d0, ushort4v* __restrict__ d1, ushort4v* __restrict__ d2, int n4)
{
  const float4* src = (blockIdx.y == 0) ? s0 : (blockIdx.y == 1) ? s1 : s2;
  ushort4v*    dst  = (blockIdx.y == 0) ? d0 : (blockIdx.y == 1) ? d1 : d2;
  int idx = blockIdx.x * blockDim.x + threadIdx.x;
  int stride = gridDim.x * blockDim.x;
  for (int i = idx; i < n4; i += stride) {
    float4 v = src[i];
    ushort4v o;
    o[0] = f2bf(v.x); o[1] = f2bf(v.y); o[2] = f2bf(v.z); o[3] = f2bf(v.w);
    dst[i] = o;
  }
}

// Convert 4 weight matrices fp32 -> bf16
__global__ __launch_bounds__(256) void cvtW_f32_bf16(
    const float4* __restrict__ s0, const float4* __restrict__ s1,
    const float4* __restrict__ s2, const float4* __restrict__ s3,
    ushort4v* __restrict__ d0, ushort4v* __restrict__ d1,
    ushort4v* __restrict__ d2, ushort4v* __restrict__ d3, int n4)
{
  const float4* src = (blockIdx.y == 0) ? s0 : (blockIdx.y == 1) ? s1 : (blockIdx.y == 2) ? s2 : s3;
  ushort4v*    dst  = (blockIdx.y == 0) ? d0 : (blockIdx.y == 1) ? d1 : (blockIdx.y == 2) ? d2 : d3;
  int idx = blockIdx.x * blockDim.x + threadIdx.x;
  int stride = gridDim.x * blockDim.x;
  for (int i = idx; i < n4; i += stride) {
    float4 v = src[i];
    ushort4v o;
    o[0] = f2bf(v.x); o[1] = f2bf(v.y); o[2] = f2bf(v.z); o[3] = f2bf(v.w);
    dst[i] = o;
  }
}

// out[m,n] = sum_k X[m,k]*W[n,k] + bias[n].  LDS-staged (global_load_lds w=16),
// block tile 128x128, BK=64, 4 waves (wave tile 64x64 = 4x4 MFMA).
// LDS layout [row][chunk] 8 chunks of 16B per row; source chunk XOR-swizzled by row&7
// so frag ds_read_b128 is ~conflict-free.
template <bool F32OUT>
__global__ __launch_bounds__(256, 4) void gemm_nt_bias(
    const unsigned short* __restrict__ X,
    const unsigned short* __restrict__ W,
    const float* __restrict__ bias,
    void* __restrict__ outv)
{
  __shared__ unsigned short As[128 * 64];   // 16 KB
  __shared__ unsigned short Bs[128 * 64];   // 16 KB

  const int K = Ee, N = Ee;
  const int lane = threadIdx.x & 63;
  const int wave = threadIdx.x >> 6;
  const int r16  = lane & 15;
  const int oct  = lane >> 4;
  const int m_blk = blockIdx.y * 128;
  const int n_blk = blockIdx.x * 128;
  const int wm = (wave >> 1) * 64;
  const int wn = (wave & 1) * 64;

  // staging map: lane -> (row8 = lane>>3, stored chunk = lane&7); src chunk = stored ^ row8
  const int row8  = lane >> 3;
  const int chSt  = lane & 7;
  const int chSrc = chSt ^ row8;

  floatx4 acc[4][4];
  #pragma unroll
  for (int a = 0; a < 4; ++a)
    #pragma unroll
    for (int b = 0; b < 4; ++b)
      acc[a][b] = (floatx4)(0.0f);

  for (int kb = 0; kb < K; kb += 64) {
    __syncthreads();   // previous tile fully consumed
    #pragma unroll
    for (int t = 0; t < 4; ++t) {
      const int rbase = t * 32 + wave * 8;           // 0..127 over (t,wave)
      const int arow = m_blk + rbase + row8;
      const int brow = n_blk + rbase + row8;
      __builtin_amdgcn_global_load_lds(
          (const __attribute__((address_space(1))) unsigned int*)(X + (size_t)arow * K + kb + chSrc * 8),
          (__attribute__((address_space(3))) unsigned int*)(As + rbase * 64), 16, 0, 0);
      __builtin_amdgcn_global_load_lds(
          (const __attribute__((address_space(1))) unsigned int*)(W + (size_t)brow * K + kb + chSrc * 8),
          (__attribute__((address_space(3))) unsigned int*)(Bs + rbase * 64), 16, 0, 0);
    }
    __syncthreads();   // staging visible (compiler drains vmcnt)

    #pragma unroll
    for (int s = 0; s < 2; ++s) {
      bf16x8 af[4], bfq[4];
      #pragma unroll
      for (int mi = 0; mi < 4; ++mi) {
        const int row = wm + mi * 16 + r16;
        af[mi] = *(const bf16x8*)(As + row * 64 + ((s * 4 + oct) ^ (r16 & 7)) * 8);
      }
      #pragma unroll
      for (int ni = 0; ni < 4; ++ni) {
        const int row = wn + ni * 16 + r16;
        bfq[ni] = *(const bf16x8*)(Bs + row * 64 + ((s * 4 + oct) ^ (r16 & 7)) * 8);
      }
      #pragma unroll
      for (int mi = 0; mi < 4; ++mi)
        #pragma unroll
        for (int ni = 0; ni < 4; ++ni)
          acc[mi][ni] = __builtin_amdgcn_mfma_f32_16x16x32_bf16(af[mi], bfq[ni], acc[mi][ni], 0, 0, 0);
    }
  }

  #pragma unroll
  for (int mi = 0; mi < 4; ++mi)
    #pragma unroll
    for (int ni = 0; ni < 4; ++ni)
      #pragma unroll
      for (int r = 0; r < 4; ++r) {
        const int m = m_blk + wm + mi * 16 + oct * 4 + r;
        const int n = n_blk + wn + ni * 16 + r16;
        const float val = acc[mi][ni][r] + bias[n];
        if (F32OUT) ((float*)outv)[(size_t)m * N + n] = val;
        else        ((unsigned short*)outv)[(size_t)m * N + n] = f2bf(val);
      }
}

// 2 blocks (512 thr = 8 waves) per (b,h,c) slice; grid (256, 2).
// Wave handles stripes rt0 = 2*wave + blockIdx.y and 31-rt0 (balanced pairing).
// LDS: V^T [64][512] XOR-swizzled (64 KB) + per-wave P transpose scratch (10 KB).
__global__ __launch_bounds__(512, 4) void attn_kernel(
    const unsigned short* __restrict__ Q,
    const unsigned short* __restrict__ Kb,
    const unsigned short* __restrict__ V,
    float* __restrict__ attn_out,           // write-only now
    unsigned short* __restrict__ ctx)
{
  __shared__ unsigned short VT[HDd][Ss];        // 64 KB
  __shared__ unsigned short scr[8][16 * RS];    // 8 x 1280 B

  const int slice = blockIdx.x;            // (b*H + h)*C + c
  const int c  = slice & (Cc - 1);
  const int bh = slice >> 3;
  const int h  = bh & (Hh - 1);
  const int b  = bh >> 3;
  const size_t tokBase  = (size_t)(b * Cc + c) * Ss;
  const size_t attnBase = (size_t)slice * Ss * Ss;

  const int tid  = threadIdx.x;
  const int lane = tid & 63;
  const int wave = tid >> 6;
  const int r16  = lane & 15;
  const int oct  = lane >> 4;
  unsigned short* sw = scr[wave];

  // ---- stage V^T into LDS (transpose with XOR swizzle) ----
  {
    const int jrow = tid >> 3;        // 0..63
    const int d0   = (tid & 7) * 8;   // 8 d's per thread
    #pragma unroll
    for (int pass = 0; pass < 8; ++pass) {
      const int j = pass * 64 + jrow;
      const uint4 u = *(const uint4*)(V + (tokBase + j) * Ee + h * HDd + d0);
      const unsigned short e[8] = {
        (unsigned short)(u.x & 0xffffu), (unsigned short)(u.x >> 16),
        (unsigned short)(u.y & 0xffffu), (unsigned short)(u.y >> 16),
        (unsigned short)(u.z & 0xffffu), (unsigned short)(u.z >> 16),
        (unsigned short)(u.w & 0xffffu), (unsigned short)(u.w >> 16)};
      #pragma unroll
      for (int k = 0; k < 8; ++k)
        VT[d0 + k][j ^ (k << 3)] = e[k];   // (d0+k)&7 == k
    }
  }
  __syncthreads();

  const int rt0 = 2 * wave + blockIdx.y;   // 0..15
  for (int t = 0; t < 2; ++t) {
    const int rt = t ? (31 - rt0) : rt0;   // pair sums to 31 -> balanced waves
    const int I  = rt * 16;
    const int ibase = I + oct * 4;

    const unsigned short* qrow = Q + (tokBase + I + r16) * Ee + h * HDd + oct * 8;
    const bf16x8 qa0 = *(const bf16x8*)(qrow);
    const bf16x8 qa1 = *(const bf16x8*)(qrow + 32);

    floatx4 sc[32];
    #pragma unroll
    for (int ct = 0; ct < 32; ++ct) {
      if (ct <= rt) {
        const unsigned short* krow = Kb + (tokBase + ct * 16 + r16) * Ee + h * HDd + oct * 8;
        const bf16x8 kb0 = *(const bf16x8*)(krow);
        const bf16x8 kb1 = *(const bf16x8*)(krow + 32);
        floatx4 a = (floatx4)(0.0f);
        a = __builtin_amdgcn_mfma_f32_16x16x32_bf16(qa0, kb0, a, 0, 0, 0);
        a = __builtin_amdgcn_mfma_f32_16x16x32_bf16(qa1, kb1, a, 0, 0, 0);
        sc[ct] = a;
      }
    }

    float mx[4] = {-INFINITY, -INFINITY, -INFINITY, -INFINITY};
    #pragma unroll
    for (int ct = 0; ct < 32; ++ct) {
      if (ct <= rt) {
        #pragma unroll
        for (int r = 0; r < 4; ++r) {
          const int i = ibase + r;
          const int j = ct * 16 + r16;
          const bool allowed = ((j <= i) && (j + LOCALW >= i)) || (((j & 3) == 0) && (j < i));
          const float s = allowed ? sc[ct][r] * 0.125f : -INFINITY;
          sc[ct][r] = s;
          mx[r] = fmaxf(mx[r], s);
        }
      }
    }
    #pragma unroll
    for (int m = 1; m <= 8; m <<= 1)
      #pragma unroll
      for (int r = 0; r < 4; ++r)
        mx[r] = fmaxf(mx[r], __shfl_xor(mx[r], m, 64));

    float sum[4] = {0.0f, 0.0f, 0.0f, 0.0f};
    #pragma unroll
    for (int ct = 0; ct < 32; ++ct) {
      if (ct <= rt) {
        #pragma unroll
        for (int r = 0; r < 4; ++r) {
          const float p = __expf(sc[ct][r] - mx[r]);
          sc[ct][r] = p;
          sum[r] += p;
        }
      }
    }
    #pragma unroll
    for (int m = 1; m <= 8; m <<= 1)
      #pragma unroll
      for (int r = 0; r < 4; ++r)
        sum[r] += __shfl_xor(sum[r], m, 64);
    float inv[4];
    #pragma unroll
    for (int r = 0; r < 4; ++r) inv[r] = 1.0f / sum[r];

    // normalize in place, then store dense attn stripe (zeros beyond diagonal)
    #pragma unroll
    for (int ct = 0; ct < 32; ++ct) {
      #pragma unroll
      for (int r = 0; r < 4; ++r) {
        const float p = (ct <= rt) ? sc[ct][r] * inv[r] : 0.0f;
        if (ct <= rt) sc[ct][r] = p;
        attn_out[attnBase + (size_t)(ibase + r) * Ss + ct * 16 + r16] = p;
      }
    }

    // ---- PV: transpose P (C-layout -> A-layout) via per-wave LDS scratch ----
    floatx4 cacc[4];
    #pragma unroll
    for (int dt = 0; dt < 4; ++dt) cacc[dt] = (floatx4)(0.0f);

    const int jcMax = rt >> 1;
    #pragma unroll
    for (int jc = 0; jc < 16; ++jc) {
      if (jc <= jcMax) {
        #pragma unroll
        for (int half = 0; half < 2; ++half) {
          const int ct = jc * 2 + half;
          #pragma unroll
          for (int r = 0; r < 4; ++r) {
            const float p = (ct <= rt) ? sc[ct][r] : 0.0f;
            sw[(oct * 4 + r) * RS + half * 16 + r16] = f2bf(p);
          }
        }
        // A-frag: rows r16, k = oct*8..+7 within this 32-col block (contiguous 16 B)
        const bf16x8 pa = *(const bf16x8*)(&sw[r16 * RS + oct * 8]);
        #pragma unroll
        for (int dt = 0; dt < 4; ++dt) {
          const int d = dt * 16 + r16;
          const int col = (jc * 32 + oct * 8) ^ ((d & 7) << 3);
          const bf16x8 vb = *(const bf16x8*)(&VT[d][col]);
          cacc[dt] = __builtin_amdgcn_mfma_f32_16x16x32_bf16(pa, vb, cacc[dt], 0, 0, 0);
        }
      }
    }

    #pragma unroll
    for (int dt = 0; dt < 4; ++dt)
      #pragma unroll
      for (int r = 0; r < 4; ++r)
        ctx[(tokBase + ibase + r) * Ee + h * HDd + dt * 16 + r16] = f2bf(cacc[dt][r]);
  }
}

extern "C" void kernel_launch(void* const* d_in, const int* in_sizes, int n_in,
                              void* d_out, int out_size, void* d_ws, size_t ws_size,
                              hipStream_t stream) {
  const float* query = (const float*)d_in[0];
  const float* key_  = (const float*)d_in[1];
  const float* value = (const float*)d_in[2];
  const float* Wq = (const float*)d_in[3];
  const float* bq = (const float*)d_in[4];
  const float* Wk = (const float*)d_in[5];
  const float* bk = (const float*)d_in[6];
  const float* Wv = (const float*)d_in[7];
  const float* bv = (const float*)d_in[8];
  const float* Wo = (const float*)d_in[9];
  const float* bo = (const float*)d_in[10];

  float* out  = (float*)d_out;                          // [B,C,S,E] fp32
  float* attn = out + (size_t)Bb*Cc*Ss*Ee;              // [B,H,C,S,S] fp32

  unsigned short* ws = (unsigned short*)d_ws;
  unsigned short* qb  = ws;
  unsigned short* kb  = qb  + (size_t)NTOK * Ee;
  unsigned short* vb  = kb  + (size_t)NTOK * Ee;
  unsigned short* Qw  = vb  + (size_t)NTOK * Ee;
  unsigned short* Kw  = Qw  + (size_t)NTOK * Ee;
  unsigned short* Vw  = Kw  + (size_t)NTOK * Ee;
  unsigned short* Cw  = Vw  + (size_t)NTOK * Ee;
  unsigned short* Wqb = Cw  + (size_t)NTOK * Ee;
  unsigned short* Wkb = Wqb + (size_t)Ee * Ee;
  unsigned short* Wvb = Wkb + (size_t)Ee * Ee;
  unsigned short* Wob = Wvb + (size_t)Ee * Ee;

  const int n4big = NTOK * Ee / 4;
  const int n4w   = Ee * Ee / 4;
  cvt3_f32_bf16<<<dim3(1024, 3), 256, 0, stream>>>(
      (const float4*)query, (const float4*)key_, (const float4*)value,
      (ushort4v*)qb, (ushort4v*)kb, (ushort4v*)vb, n4big);
  cvtW_f32_bf16<<<dim3(128, 4), 256, 0, stream>>>(
      (const float4*)Wq, (const float4*)Wk, (const float4*)Wv, (const float4*)Wo,
      (ushort4v*)Wqb, (ushort4v*)Wkb, (ushort4v*)Wvb, (ushort4v*)Wob, n4w);

  dim3 blk(256);
  dim3 ggrid(Ee / 128, NTOK / 128);   // (4, 128)
  gemm_nt_bias<false><<<ggrid, blk, 0, stream>>>(qb, Wqb, bq, Qw);
  gemm_nt_bias<false><<<ggrid, blk, 0, stream>>>(kb, Wkb, bk, Kw);
  gemm_nt_bias<false><<<ggrid, blk, 0, stream>>>(vb, Wvb, bv, Vw);

  attn_kernel<<<dim3(Bb*Hh*Cc, 2), 512, 0, stream>>>(Qw, Kw, Vw, attn, Cw);

  gemm_nt_bias<true><<<ggrid, blk, 0, stream>>>(Cw, Wob, bo, out);
}

// Round 5
// 640.809 us; speedup vs baseline: 1.5555x; 1.5555x over previous
//
#include <hip/hip_runtime.h>
#include <math.h>

#define Bb 4
#define Cc 8
#define Ss 512
#define Ee 512
#define Hh 8
#define HDd 64
#define LOCALW 32
#define NTOK (Bb*Cc*Ss)   // 16384 rows
#define RS 40             // P-scratch row stride (shorts): 80 B, 16B-aligned

typedef __attribute__((ext_vector_type(8))) __bf16 bf16x8;
typedef __attribute__((ext_vector_type(4))) float floatx4;
typedef __attribute__((ext_vector_type(4))) unsigned short ushort4v;

__device__ __forceinline__ unsigned short f2bf(float f) {
  union { float f; unsigned int i; } x; x.f = f;
  unsigned int r = x.i + 0x7fffu + ((x.i >> 16) & 1u);  // RNE
  return (unsigned short)(r >> 16);
}

// Convert q,k,v fp32 -> bf16 (blockIdx.y selects tensor)
__global__ __launch_bounds__(256) void cvt3_f32_bf16(
    const float4* __restrict__ s0, const float4* __restrict__ s1, const float4* __restrict__ s2,
    ushort4v* __restrict__ d0, ushort4v* __restrict__ d1, ushort4v* __restrict__ d2, int n4)
{
  const float4* src = (blockIdx.y == 0) ? s0 : (blockIdx.y == 1) ? s1 : s2;
  ushort4v*    dst  = (blockIdx.y == 0) ? d0 : (blockIdx.y == 1) ? d1 : d2;
  int idx = blockIdx.x * blockDim.x + threadIdx.x;
  int stride = gridDim.x * blockDim.x;
  for (int i = idx; i < n4; i += stride) {
    float4 v = src[i];
    ushort4v o;
    o[0] = f2bf(v.x); o[1] = f2bf(v.y); o[2] = f2bf(v.z); o[3] = f2bf(v.w);
    dst[i] = o;
  }
}

// Convert 4 weight matrices fp32 -> bf16
__global__ __launch_bounds__(256) void cvtW_f32_bf16(
    const float4* __restrict__ s0, const float4* __restrict__ s1,
    const float4* __restrict__ s2, const float4* __restrict__ s3,
    ushort4v* __restrict__ d0, ushort4v* __restrict__ d1,
    ushort4v* __restrict__ d2, ushort4v* __restrict__ d3, int n4)
{
  const float4* src = (blockIdx.y == 0) ? s0 : (blockIdx.y == 1) ? s1 : (blockIdx.y == 2) ? s2 : s3;
  ushort4v*    dst  = (blockIdx.y == 0) ? d0 : (blockIdx.y == 1) ? d1 : (blockIdx.y == 2) ? d2 : d3;
  int idx = blockIdx.x * blockDim.x + threadIdx.x;
  int stride = gridDim.x * blockDim.x;
  for (int i = idx; i < n4; i += stride) {
    float4 v = src[i];
    ushort4v o;
    o[0] = f2bf(v.x); o[1] = f2bf(v.y); o[2] = f2bf(v.z); o[3] = f2bf(v.w);
    dst[i] = o;
  }
}

// out[m,n] = sum_k X[m,k]*W[n,k] + bias[n].  LDS-staged (global_load_lds w=16),
// block tile 128x128, BK=64, 4 waves (wave tile 64x64 = 4x4 MFMA).
// blockIdx.z selects (X,W,bias,out) triple so all 3 projections ride one dispatch.
// LDS layout [row][chunk]: stored chunk c holds source chunk c ^ (row&7) -> ~conflict-free b128.
template <bool F32OUT>
__global__ __launch_bounds__(256, 4) void gemm_nt_bias3(
    const unsigned short* __restrict__ X0, const unsigned short* __restrict__ X1,
    const unsigned short* __restrict__ X2,
    const unsigned short* __restrict__ W0, const unsigned short* __restrict__ W1,
    const unsigned short* __restrict__ W2,
    const float* __restrict__ bias0, const float* __restrict__ bias1,
    const float* __restrict__ bias2,
    void* __restrict__ out0, void* __restrict__ out1, void* __restrict__ out2)
{
  const int z = blockIdx.z;
  const unsigned short* X = (z == 0) ? X0 : (z == 1) ? X1 : X2;
  const unsigned short* W = (z == 0) ? W0 : (z == 1) ? W1 : W2;
  const float* bias        = (z == 0) ? bias0 : (z == 1) ? bias1 : bias2;
  void* outv               = (z == 0) ? out0 : (z == 1) ? out1 : out2;

  __shared__ unsigned short As[128 * 64];   // 16 KB
  __shared__ unsigned short Bs[128 * 64];   // 16 KB

  const int K = Ee, N = Ee;
  const int lane = threadIdx.x & 63;
  const int wave = threadIdx.x >> 6;
  const int r16  = lane & 15;
  const int oct  = lane >> 4;
  const int m_blk = blockIdx.y * 128;
  const int n_blk = blockIdx.x * 128;
  const int wm = (wave >> 1) * 64;
  const int wn = (wave & 1) * 64;

  const int row8  = lane >> 3;
  const int chSt  = lane & 7;
  const int chSrc = chSt ^ row8;

  floatx4 acc[4][4];
  #pragma unroll
  for (int a = 0; a < 4; ++a)
    #pragma unroll
    for (int b = 0; b < 4; ++b)
      acc[a][b] = (floatx4)(0.0f);

  for (int kb = 0; kb < K; kb += 64) {
    __syncthreads();
    #pragma unroll
    for (int t = 0; t < 4; ++t) {
      const int rbase = t * 32 + wave * 8;
      const int arow = m_blk + rbase + row8;
      const int brow = n_blk + rbase + row8;
      __builtin_amdgcn_global_load_lds(
          (const __attribute__((address_space(1))) unsigned int*)(X + (size_t)arow * K + kb + chSrc * 8),
          (__attribute__((address_space(3))) unsigned int*)(As + rbase * 64), 16, 0, 0);
      __builtin_amdgcn_global_load_lds(
          (const __attribute__((address_space(1))) unsigned int*)(W + (size_t)brow * K + kb + chSrc * 8),
          (__attribute__((address_space(3))) unsigned int*)(Bs + rbase * 64), 16, 0, 0);
    }
    __syncthreads();

    #pragma unroll
    for (int s = 0; s < 2; ++s) {
      bf16x8 af[4], bfq[4];
      #pragma unroll
      for (int mi = 0; mi < 4; ++mi) {
        const int row = wm + mi * 16 + r16;
        af[mi] = *(const bf16x8*)(As + row * 64 + ((s * 4 + oct) ^ (r16 & 7)) * 8);
      }
      #pragma unroll
      for (int ni = 0; ni < 4; ++ni) {
        const int row = wn + ni * 16 + r16;
        bfq[ni] = *(const bf16x8*)(Bs + row * 64 + ((s * 4 + oct) ^ (r16 & 7)) * 8);
      }
      #pragma unroll
      for (int mi = 0; mi < 4; ++mi)
        #pragma unroll
        for (int ni = 0; ni < 4; ++ni)
          acc[mi][ni] = __builtin_amdgcn_mfma_f32_16x16x32_bf16(af[mi], bfq[ni], acc[mi][ni], 0, 0, 0);
    }
  }

  #pragma unroll
  for (int mi = 0; mi < 4; ++mi)
    #pragma unroll
    for (int ni = 0; ni < 4; ++ni)
      #pragma unroll
      for (int r = 0; r < 4; ++r) {
        const int m = m_blk + wm + mi * 16 + oct * 4 + r;
        const int n = n_blk + wn + ni * 16 + r16;
        const float val = acc[mi][ni][r] + bias[n];
        if (F32OUT) ((float*)outv)[(size_t)m * N + n] = val;
        else        ((unsigned short*)outv)[(size_t)m * N + n] = f2bf(val);
      }
}

// 2 blocks (512 thr = 8 waves) per (b,h,c) slice; grid (256, 2).
// Wave handles stripes rt0 = 2*wave + blockIdx.y and 31-rt0 (balanced pairing).
// LDS: V^T [64][512] XOR-swizzled (64 KB) + per-wave P transpose scratch (10 KB).
// launch_bounds(512,2): VGPR budget 256 so sc[32] (128 VGPRs) stays in registers —
// (512,4) in round 4 forced VGPR=64 and spilled ~1.2 GB to scratch.
__global__ __launch_bounds__(512, 2) void attn_kernel(
    const unsigned short* __restrict__ Q,
    const unsigned short* __restrict__ Kb,
    const unsigned short* __restrict__ V,
    float* __restrict__ attn_out,           // write-only
    unsigned short* __restrict__ ctx)
{
  __shared__ unsigned short VT[HDd][Ss];        // 64 KB
  __shared__ unsigned short scr[8][16 * RS];    // 8 x 1280 B

  const int slice = blockIdx.x;            // (b*H + h)*C + c
  const int c  = slice & (Cc - 1);
  const int bh = slice >> 3;
  const int h  = bh & (Hh - 1);
  const int b  = bh >> 3;
  const size_t tokBase  = (size_t)(b * Cc + c) * Ss;
  const size_t attnBase = (size_t)slice * Ss * Ss;

  const int tid  = threadIdx.x;
  const int lane = tid & 63;
  const int wave = tid >> 6;
  const int r16  = lane & 15;
  const int oct  = lane >> 4;
  unsigned short* sw = scr[wave];

  // ---- stage V^T into LDS (transpose with XOR swizzle) ----
  {
    const int jrow = tid >> 3;        // 0..63
    const int d0   = (tid & 7) * 8;   // 8 d's per thread
    #pragma unroll
    for (int pass = 0; pass < 8; ++pass) {
      const int j = pass * 64 + jrow;
      const uint4 u = *(const uint4*)(V + (tokBase + j) * Ee + h * HDd + d0);
      const unsigned short e[8] = {
        (unsigned short)(u.x & 0xffffu), (unsigned short)(u.x >> 16),
        (unsigned short)(u.y & 0xffffu), (unsigned short)(u.y >> 16),
        (unsigned short)(u.z & 0xffffu), (unsigned short)(u.z >> 16),
        (unsigned short)(u.w & 0xffffu), (unsigned short)(u.w >> 16)};
      #pragma unroll
      for (int k = 0; k < 8; ++k)
        VT[d0 + k][j ^ (k << 3)] = e[k];   // (d0+k)&7 == k
    }
  }
  __syncthreads();

  const int rt0 = 2 * wave + blockIdx.y;   // 0..15
  for (int t = 0; t < 2; ++t) {
    const int rt = t ? (31 - rt0) : rt0;   // pair sums to 31 -> balanced waves
    const int I  = rt * 16;
    const int ibase = I + oct * 4;

    const unsigned short* qrow = Q + (tokBase + I + r16) * Ee + h * HDd + oct * 8;
    const bf16x8 qa0 = *(const bf16x8*)(qrow);
    const bf16x8 qa1 = *(const bf16x8*)(qrow + 32);

    floatx4 sc[32];
    #pragma unroll
    for (int ct = 0; ct < 32; ++ct) {
      if (ct <= rt) {
        const unsigned short* krow = Kb + (tokBase + ct * 16 + r16) * Ee + h * HDd + oct * 8;
        const bf16x8 kb0 = *(const bf16x8*)(krow);
        const bf16x8 kb1 = *(const bf16x8*)(krow + 32);
        floatx4 a = (floatx4)(0.0f);
        a = __builtin_amdgcn_mfma_f32_16x16x32_bf16(qa0, kb0, a, 0, 0, 0);
        a = __builtin_amdgcn_mfma_f32_16x16x32_bf16(qa1, kb1, a, 0, 0, 0);
        sc[ct] = a;
      }
    }

    float mx[4] = {-INFINITY, -INFINITY, -INFINITY, -INFINITY};
    #pragma unroll
    for (int ct = 0; ct < 32; ++ct) {
      if (ct <= rt) {
        #pragma unroll
        for (int r = 0; r < 4; ++r) {
          const int i = ibase + r;
          const int j = ct * 16 + r16;
          const bool allowed = ((j <= i) && (j + LOCALW >= i)) || (((j & 3) == 0) && (j < i));
          const float s = allowed ? sc[ct][r] * 0.125f : -INFINITY;
          sc[ct][r] = s;
          mx[r] = fmaxf(mx[r], s);
        }
      }
    }
    #pragma unroll
    for (int m = 1; m <= 8; m <<= 1)
      #pragma unroll
      for (int r = 0; r < 4; ++r)
        mx[r] = fmaxf(mx[r], __shfl_xor(mx[r], m, 64));

    float sum[4] = {0.0f, 0.0f, 0.0f, 0.0f};
    #pragma unroll
    for (int ct = 0; ct < 32; ++ct) {
      if (ct <= rt) {
        #pragma unroll
        for (int r = 0; r < 4; ++r) {
          const float p = __expf(sc[ct][r] - mx[r]);
          sc[ct][r] = p;
          sum[r] += p;
        }
      }
    }
    #pragma unroll
    for (int m = 1; m <= 8; m <<= 1)
      #pragma unroll
      for (int r = 0; r < 4; ++r)
        sum[r] += __shfl_xor(sum[r], m, 64);
    float inv[4];
    #pragma unroll
    for (int r = 0; r < 4; ++r) inv[r] = 1.0f / sum[r];

    // normalize in place, then store dense attn stripe (zeros beyond diagonal)
    #pragma unroll
    for (int ct = 0; ct < 32; ++ct) {
      #pragma unroll
      for (int r = 0; r < 4; ++r) {
        const float p = (ct <= rt) ? sc[ct][r] * inv[r] : 0.0f;
        if (ct <= rt) sc[ct][r] = p;
        attn_out[attnBase + (size_t)(ibase + r) * Ss + ct * 16 + r16] = p;
      }
    }

    // ---- PV: transpose P (C-layout -> A-layout) via per-wave LDS scratch ----
    floatx4 cacc[4];
    #pragma unroll
    for (int dt = 0; dt < 4; ++dt) cacc[dt] = (floatx4)(0.0f);

    const int jcMax = rt >> 1;
    #pragma unroll
    for (int jc = 0; jc < 16; ++jc) {
      if (jc <= jcMax) {
        #pragma unroll
        for (int half = 0; half < 2; ++half) {
          const int ct = jc * 2 + half;
          #pragma unroll
          for (int r = 0; r < 4; ++r) {
            const float p = (ct <= rt) ? sc[ct][r] : 0.0f;
            sw[(oct * 4 + r) * RS + half * 16 + r16] = f2bf(p);
          }
        }
        const bf16x8 pa = *(const bf16x8*)(&sw[r16 * RS + oct * 8]);
        #pragma unroll
        for (int dt = 0; dt < 4; ++dt) {
          const int d = dt * 16 + r16;
          const int col = (jc * 32 + oct * 8) ^ ((d & 7) << 3);
          const bf16x8 vb = *(const bf16x8*)(&VT[d][col]);
          cacc[dt] = __builtin_amdgcn_mfma_f32_16x16x32_bf16(pa, vb, cacc[dt], 0, 0, 0);
        }
      }
    }

    #pragma unroll
    for (int dt = 0; dt < 4; ++dt)
      #pragma unroll
      for (int r = 0; r < 4; ++r)
        ctx[(tokBase + ibase + r) * Ee + h * HDd + dt * 16 + r16] = f2bf(cacc[dt][r]);
  }
}

extern "C" void kernel_launch(void* const* d_in, const int* in_sizes, int n_in,
                              void* d_out, int out_size, void* d_ws, size_t ws_size,
                              hipStream_t stream) {
  const float* query = (const float*)d_in[0];
  const float* key_  = (const float*)d_in[1];
  const float* value = (const float*)d_in[2];
  const float* Wq = (const float*)d_in[3];
  const float* bq = (const float*)d_in[4];
  const float* Wk = (const float*)d_in[5];
  const float* bk = (const float*)d_in[6];
  const float* Wv = (const float*)d_in[7];
  const float* bv = (const float*)d_in[8];
  const float* Wo = (const float*)d_in[9];
  const float* bo = (const float*)d_in[10];

  float* out  = (float*)d_out;                          // [B,C,S,E] fp32
  float* attn = out + (size_t)Bb*Cc*Ss*Ee;              // [B,H,C,S,S] fp32

  unsigned short* ws = (unsigned short*)d_ws;
  unsigned short* qb  = ws;
  unsigned short* kb  = qb  + (size_t)NTOK * Ee;
  unsigned short* vb  = kb  + (size_t)NTOK * Ee;
  unsigned short* Qw  = vb  + (size_t)NTOK * Ee;
  unsigned short* Kw  = Qw  + (size_t)NTOK * Ee;
  unsigned short* Vw  = Kw  + (size_t)NTOK * Ee;
  unsigned short* Cw  = Vw  + (size_t)NTOK * Ee;
  unsigned short* Wqb = Cw  + (size_t)NTOK * Ee;
  unsigned short* Wkb = Wqb + (size_t)Ee * Ee;
  unsigned short* Wvb = Wkb + (size_t)Ee * Ee;
  unsigned short* Wob = Wvb + (size_t)Ee * Ee;

  const int n4big = NTOK * Ee / 4;
  const int n4w   = Ee * Ee / 4;
  cvt3_f32_bf16<<<dim3(1024, 3), 256, 0, stream>>>(
      (const float4*)query, (const float4*)key_, (const float4*)value,
      (ushort4v*)qb, (ushort4v*)kb, (ushort4v*)vb, n4big);
  cvtW_f32_bf16<<<dim3(128, 4), 256, 0, stream>>>(
      (const float4*)Wq, (const float4*)Wk, (const float4*)Wv, (const float4*)Wo,
      (ushort4v*)Wqb, (ushort4v*)Wkb, (ushort4v*)Wvb, (ushort4v*)Wob, n4w);

  dim3 blk(256);
  // fused q/k/v projections: z = tensor index
  gemm_nt_bias3<false><<<dim3(Ee / 128, NTOK / 128, 3), blk, 0, stream>>>(
      qb, kb, vb, Wqb, Wkb, Wvb, bq, bk, bv, Qw, Kw, Vw);

  attn_kernel<<<dim3(Bb*Hh*Cc, 2), 512, 0, stream>>>(Qw, Kw, Vw, attn, Cw);

  gemm_nt_bias3<true><<<dim3(Ee / 128, NTOK / 128, 1), blk, 0, stream>>>(
      Cw, Cw, Cw, Wob, Wob, Wob, bo, bo, bo, out, out, out);
}